// Round 2
// baseline (4627.912 us; speedup 1.0000x reference)
//
#include <hip/hip_runtime.h>
#include <hip/hip_bf16.h>

// ToxDL GCN network, fp32 baseline (round 1: int32 index fix).
// Pipeline per GCN layer: h = act @ W  (tiled fp32 GEMM)
//                         agg[n] = h[n] * (1/deg[n])          (self-loop term)
//                         agg[dst] += h[src]*dis[src]*dis[dst] (edge scatter, f32 atomics)
//                         agg = relu(agg + b)                  (layers 1-3)
// Then mean-pool per graph, L2-normalize, concat with vector, 3-layer MLP head.

#define N_NODES 10000
#define N_EDGES 160000
#define NGRAPH  64

// ---------------- degree kernels ----------------
__global__ __launch_bounds__(256) void deg_init(float* deg, int n) {
    int i = blockIdx.x * 256 + threadIdx.x;
    if (i < n) deg[i] = 1.0f;  // self-loop
}

__global__ __launch_bounds__(256) void deg_count(const int* __restrict__ dst, float* deg, int E) {
    int e = blockIdx.x * 256 + threadIdx.x;
    if (e < E) atomicAdd(&deg[dst[e]], 1.0f);
}

__global__ __launch_bounds__(256) void deg_fin(float* dis_deg, float* invdeg, int n) {
    int i = blockIdx.x * 256 + threadIdx.x;
    if (i < n) {
        float d = dis_deg[i];
        dis_deg[i] = 1.0f / sqrtf(d);
        invdeg[i] = 1.0f / d;
    }
}

// ---------------- fp32 tiled GEMM: C[M,N] = A[M,K] @ W[K,N] ----------------
// 64x64 tile, BK=16, 256 threads, 4x4 acc per thread.
__global__ __launch_bounds__(256) void gemm_f32(const float* __restrict__ A,
                                                const float* __restrict__ W,
                                                float* __restrict__ C,
                                                int M, int K, int N) {
    __shared__ float As[16][65];
    __shared__ float Bs[16][65];
    int tid = threadIdx.x;
    int tx = tid & 15, ty = tid >> 4;
    int row0 = blockIdx.y * 64, col0 = blockIdx.x * 64;
    float acc[4][4] = {};

    int ac = tid & 15;            // A col within tile
    int ar0 = (tid >> 4) * 4;     // A first row within tile
    int bn = tid & 63;            // B col within tile
    int bc0 = tid >> 6;           // B first row (0..3), step 4

    for (int k0 = 0; k0 < K; k0 += 16) {
#pragma unroll
        for (int i = 0; i < 4; i++) {
            int r = row0 + ar0 + i;
            As[ac][ar0 + i] = (r < M) ? A[(long)r * K + k0 + ac] : 0.0f;
        }
#pragma unroll
        for (int i = 0; i < 4; i++) {
            int c = bc0 + i * 4;
            Bs[c][bn] = W[(long)(k0 + c) * N + col0 + bn];
        }
        __syncthreads();
#pragma unroll
        for (int k = 0; k < 16; k++) {
            float a[4], b[4];
#pragma unroll
            for (int i = 0; i < 4; i++) a[i] = As[k][ty * 4 + i];
#pragma unroll
            for (int j = 0; j < 4; j++) b[j] = Bs[k][tx * 4 + j];
#pragma unroll
            for (int i = 0; i < 4; i++)
#pragma unroll
                for (int j = 0; j < 4; j++) acc[i][j] += a[i] * b[j];
        }
        __syncthreads();
    }
#pragma unroll
    for (int i = 0; i < 4; i++) {
        int r = row0 + ty * 4 + i;
        if (r < M) {
#pragma unroll
            for (int j = 0; j < 4; j++)
                C[(long)r * N + col0 + tx * 4 + j] = acc[i][j];
        }
    }
}

// ---------------- self-loop init: agg = h * invdeg[node] ----------------
// shift: log2(D/4). total = M * (D/4) float4s.
__global__ __launch_bounds__(256) void self_init(const float4* __restrict__ h,
                                                 const float* __restrict__ invdeg,
                                                 float4* __restrict__ agg,
                                                 int total, int shift) {
    int idx = blockIdx.x * 256 + threadIdx.x;
    if (idx >= total) return;
    int n = idx >> shift;
    float s = invdeg[n];
    float4 v = h[idx];
    v.x *= s; v.y *= s; v.z *= s; v.w *= s;
    agg[idx] = v;
}

// ---------------- edge scatter: agg[dst] += h[src] * dis[src]*dis[dst] ----------------
__global__ __launch_bounds__(256) void scatter_edges(const int* __restrict__ srcI,
                                                     const int* __restrict__ dstI,
                                                     const float* __restrict__ dis,
                                                     const float4* __restrict__ h,
                                                     float* __restrict__ agg,
                                                     int E, int Dv, int shift) {
    int idx = blockIdx.x * 256 + threadIdx.x;
    int e = idx >> shift;
    if (e >= E) return;
    int f = idx & (Dv - 1);
    int s = srcI[e];
    int d = dstI[e];
    float nrm = dis[s] * dis[d];
    float4 v = h[s * Dv + f];
    float* o = agg + (long)d * (Dv * 4) + f * 4;
    atomicAdd(o + 0, v.x * nrm);
    atomicAdd(o + 1, v.y * nrm);
    atomicAdd(o + 2, v.z * nrm);
    atomicAdd(o + 3, v.w * nrm);
}

// ---------------- bias + relu (in place) ----------------
__global__ __launch_bounds__(256) void bias_relu(float4* __restrict__ agg,
                                                 const float4* __restrict__ b,
                                                 int total, int dvmask) {
    int idx = blockIdx.x * 256 + threadIdx.x;
    if (idx >= total) return;
    float4 v = agg[idx];
    float4 bb = b[idx & dvmask];
    v.x = fmaxf(v.x + bb.x, 0.0f);
    v.y = fmaxf(v.y + bb.y, 0.0f);
    v.z = fmaxf(v.z + bb.z, 0.0f);
    v.w = fmaxf(v.w + bb.w, 0.0f);
    agg[idx] = v;
}

// ---------------- zero ----------------
__global__ __launch_bounds__(256) void zero_f32(float* p, int n) {
    int i = blockIdx.x * 256 + threadIdx.x;
    if (i < n) p[i] = 0.0f;
}

// ---------------- pooling accumulate: one block per node ----------------
__global__ __launch_bounds__(256) void pool_acc(const float* __restrict__ agg4,
                                                const int* __restrict__ batch,
                                                float* __restrict__ pool,
                                                float* __restrict__ cnt) {
    int n = blockIdx.x;
    int t = threadIdx.x;  // 256 = D_OUT
    int g = batch[n];
    atomicAdd(&pool[g * 256 + t], agg4[n * 256 + t]);
    if (t == 0) atomicAdd(&cnt[g], 1.0f);
}

// ---------------- head: mean, +b4, L2-normalize, concat, 3-layer MLP ----------------
__global__ __launch_bounds__(256) void head(const float* __restrict__ pool,
                                            const float* __restrict__ cnt,
                                            const float* __restrict__ b4,
                                            const float* __restrict__ vec,
                                            const float* __restrict__ cW1, const float* __restrict__ cb1,
                                            const float* __restrict__ cW2, const float* __restrict__ cb2,
                                            const float* __restrict__ cW3, const float* __restrict__ cb3,
                                            float* __restrict__ out) {
    int g = blockIdx.x;
    int t = threadIdx.x;  // 256 threads
    __shared__ float comb[512];
    __shared__ float z1s[256];
    __shared__ float z2s[64];
    __shared__ float red[4];

    float c = fmaxf(cnt[g], 1.0f);
    float pm = pool[g * 256 + t] / c + b4[t];

    float ss = pm * pm;
#pragma unroll
    for (int o = 32; o; o >>= 1) ss += __shfl_down(ss, o);
    if ((t & 63) == 0) red[t >> 6] = ss;
    __syncthreads();
    if (t == 0) {
        float tot = red[0] + red[1] + red[2] + red[3];
        red[0] = 1.0f / fmaxf(sqrtf(tot), 1e-12f);
    }
    __syncthreads();
    float scale = red[0];
    comb[t] = pm * scale;
    comb[256 + t] = vec[g * 256 + t];
    __syncthreads();

    float s1 = cb1[t];
    for (int i = 0; i < 512; i++) s1 += comb[i] * cW1[i * 256 + t];
    z1s[t] = fmaxf(s1, 0.0f);
    __syncthreads();

    if (t < 64) {
        float s2 = cb2[t];
        for (int i = 0; i < 256; i++) s2 += z1s[i] * cW2[i * 64 + t];
        z2s[t] = fmaxf(s2, 0.0f);
    }
    __syncthreads();

    if (t == 0) {
        float s3 = cb3[0];
        for (int i = 0; i < 64; i++) s3 += z2s[i] * cW3[i];
        out[g] = 1.0f / (1.0f + expf(-s3));
    }
}

extern "C" void kernel_launch(void* const* d_in, const int* in_sizes, int n_in,
                              void* d_out, int out_size, void* d_ws, size_t ws_size,
                              hipStream_t stream) {
    const float* x      = (const float*)d_in[0];
    const int*   ei     = (const int*)d_in[1];    // harness delivers integer inputs as int32
    const int*   bat    = (const int*)d_in[2];
    const float* vec    = (const float*)d_in[3];
    const float* W1 = (const float*)d_in[4];
    const float* b1 = (const float*)d_in[5];
    const float* W2 = (const float*)d_in[6];
    const float* b2 = (const float*)d_in[7];
    const float* W3 = (const float*)d_in[8];
    const float* b3 = (const float*)d_in[9];
    const float* W4 = (const float*)d_in[10];
    const float* b4 = (const float*)d_in[11];
    const float* cW1 = (const float*)d_in[12];
    const float* cb1 = (const float*)d_in[13];
    const float* cW2 = (const float*)d_in[14];
    const float* cb2 = (const float*)d_in[15];
    const float* cW3 = (const float*)d_in[16];
    const float* cb3 = (const float*)d_in[17];

    const int* srcI = ei;
    const int* dstI = ei + N_EDGES;

    float* ws = (float*)d_ws;
    float* dis    = ws;                  // N (holds deg first, then 1/sqrt(deg))
    float* invdeg = dis + N_NODES;       // N
    float* h      = invdeg + N_NODES;    // 10000*512
    float* agg    = h + N_NODES * 512;   // 10000*512
    float* pool   = agg + N_NODES * 512; // 64*256
    float* cnt    = pool + NGRAPH * 256; // 64

    // ---- degrees ----
    deg_init<<<(N_NODES + 255) / 256, 256, 0, stream>>>(dis, N_NODES);
    deg_count<<<(N_EDGES + 255) / 256, 256, 0, stream>>>(dstI, dis, N_EDGES);
    deg_fin<<<(N_NODES + 255) / 256, 256, 0, stream>>>(dis, invdeg, N_NODES);

    const int M = N_NODES;

    // ---- layer 1: x[10000,1280] @ W1[1280,512] ----
    {
        dim3 grid(512 / 64, (M + 63) / 64);
        gemm_f32<<<grid, 256, 0, stream>>>(x, W1, h, M, 1280, 512);
        int total = M * 128;  // float4s
        self_init<<<(total + 255) / 256, 256, 0, stream>>>((const float4*)h, invdeg, (float4*)agg, total, 7);
        int sc = N_EDGES * 128;
        scatter_edges<<<(sc + 255) / 256, 256, 0, stream>>>(srcI, dstI, dis, (const float4*)h, agg, N_EDGES, 128, 7);
        bias_relu<<<(total + 255) / 256, 256, 0, stream>>>((float4*)agg, (const float4*)b1, total, 127);
    }
    // ---- layers 2,3: agg[10000,512] @ W[512,512] ----
    const float* Ws[2] = {W2, W3};
    const float* bs[2] = {b2, b3};
    for (int l = 0; l < 2; l++) {
        dim3 grid(512 / 64, (M + 63) / 64);
        gemm_f32<<<grid, 256, 0, stream>>>(agg, Ws[l], h, M, 512, 512);
        int total = M * 128;
        self_init<<<(total + 255) / 256, 256, 0, stream>>>((const float4*)h, invdeg, (float4*)agg, total, 7);
        int sc = N_EDGES * 128;
        scatter_edges<<<(sc + 255) / 256, 256, 0, stream>>>(srcI, dstI, dis, (const float4*)h, agg, N_EDGES, 128, 7);
        bias_relu<<<(total + 255) / 256, 256, 0, stream>>>((float4*)agg, (const float4*)bs[l], total, 127);
    }
    // ---- layer 4: agg[10000,512] @ W4[512,256], no bias/relu here ----
    {
        dim3 grid(256 / 64, (M + 63) / 64);
        gemm_f32<<<grid, 256, 0, stream>>>(agg, W4, h, M, 512, 256);
        int total = M * 64;  // D=256 -> 64 float4 per row
        self_init<<<(total + 255) / 256, 256, 0, stream>>>((const float4*)h, invdeg, (float4*)agg, total, 6);
        int sc = N_EDGES * 64;
        scatter_edges<<<(sc + 255) / 256, 256, 0, stream>>>(srcI, dstI, dis, (const float4*)h, agg, N_EDGES, 64, 6);
    }

    // ---- pooling ----
    zero_f32<<<(NGRAPH * 256 + NGRAPH + 255) / 256, 256, 0, stream>>>(pool, NGRAPH * 256 + NGRAPH);
    pool_acc<<<M, 256, 0, stream>>>(agg, bat, pool, cnt);

    // ---- head ----
    head<<<NGRAPH, 256, 0, stream>>>(pool, cnt, b4, vec, cW1, cb1, cW2, cb2, cW3, cb3, (float*)d_out);
}

// Round 3
// 1052.336 us; speedup vs baseline: 4.3978x; 4.3978x over previous
//
#include <hip/hip_runtime.h>
#include <hip/hip_bf16.h>

// ToxDL GCN network, round 2: CSR-gather aggregation (no feature atomics).
// Per layer: h = act @ W (fp32 tiled GEMM), then per-dst gather:
//   agg[n] = relu( dis[n]*( dis[n]*h[n] + sum_e dis[src_e]*h[src_e] ) + b )
// CSR built on-device each call (counts -> scan -> fill).

#define N_NODES 10000
#define N_EDGES 160000
#define NGRAPH  64

// ---------------- zero ints ----------------
__global__ __launch_bounds__(256) void zero_i32(int* p, int n) {
    int i = blockIdx.x * 256 + threadIdx.x;
    if (i < n) p[i] = 0;
}
__global__ __launch_bounds__(256) void zero_f32(float* p, int n) {
    int i = blockIdx.x * 256 + threadIdx.x;
    if (i < n) p[i] = 0.0f;
}

// ---------------- degree count (in-edges per dst) ----------------
__global__ __launch_bounds__(256) void deg_count(const int* __restrict__ dst, int* __restrict__ degc, int E) {
    int e = blockIdx.x * 256 + threadIdx.x;
    if (e < E) atomicAdd(&degc[dst[e]], 1);
}

// ---------------- dis = 1/sqrt(deg), invdeg = 1/deg (deg includes self-loop) ----------------
__global__ __launch_bounds__(256) void deg_fin(const int* __restrict__ degc,
                                               float* __restrict__ dis, int n) {
    int i = blockIdx.x * 256 + threadIdx.x;
    if (i < n) {
        float d = (float)(degc[i] + 1);
        dis[i] = 1.0f / sqrtf(d);
    }
}

// ---------------- exclusive scan over degc -> off[0..n] ----------------
__global__ __launch_bounds__(1024) void scan_offsets(const int* __restrict__ cnt,
                                                     int* __restrict__ off, int n) {
    __shared__ int buf[1024];
    __shared__ int carry;
    int t = threadIdx.x;
    if (t == 0) { carry = 0; off[0] = 0; }
    __syncthreads();
    for (int base = 0; base < n; base += 1024) {
        int v = (base + t < n) ? cnt[base + t] : 0;
        buf[t] = v;
        __syncthreads();
#pragma unroll
        for (int o = 1; o < 1024; o <<= 1) {
            int add = (t >= o) ? buf[t - o] : 0;
            __syncthreads();
            buf[t] += add;
            __syncthreads();
        }
        if (base + t < n) off[base + t + 1] = buf[t] + carry;
        __syncthreads();
        if (t == 0) carry += buf[1023];
        __syncthreads();
    }
}

// ---------------- CSR fill: csr_src[pos]=src, csr_w[pos]=dis[src] ----------------
__global__ __launch_bounds__(256) void csr_fill(const int* __restrict__ srcI,
                                                const int* __restrict__ dstI,
                                                const int* __restrict__ off,
                                                int* __restrict__ fc,
                                                const float* __restrict__ dis,
                                                int* __restrict__ csr_src,
                                                float* __restrict__ csr_w, int E) {
    int e = blockIdx.x * 256 + threadIdx.x;
    if (e >= E) return;
    int d = dstI[e];
    int s = srcI[e];
    int pos = off[d] + atomicAdd(&fc[d], 1);
    csr_src[pos] = s;
    csr_w[pos] = dis[s];
}

// ---------------- fp32 tiled GEMM: C[M,N] = A[M,K] @ W[K,N] ----------------
__global__ __launch_bounds__(256) void gemm_f32(const float* __restrict__ A,
                                                const float* __restrict__ W,
                                                float* __restrict__ C,
                                                int M, int K, int N) {
    __shared__ float As[16][65];
    __shared__ float Bs[16][65];
    int tid = threadIdx.x;
    int tx = tid & 15, ty = tid >> 4;
    int row0 = blockIdx.y * 64, col0 = blockIdx.x * 64;
    float acc[4][4] = {};

    int ac = tid & 15;
    int ar0 = (tid >> 4) * 4;
    int bn = tid & 63;
    int bc0 = tid >> 6;

    for (int k0 = 0; k0 < K; k0 += 16) {
#pragma unroll
        for (int i = 0; i < 4; i++) {
            int r = row0 + ar0 + i;
            As[ac][ar0 + i] = (r < M) ? A[(long)r * K + k0 + ac] : 0.0f;
        }
#pragma unroll
        for (int i = 0; i < 4; i++) {
            int c = bc0 + i * 4;
            Bs[c][bn] = W[(long)(k0 + c) * N + col0 + bn];
        }
        __syncthreads();
#pragma unroll
        for (int k = 0; k < 16; k++) {
            float a[4], b[4];
#pragma unroll
            for (int i = 0; i < 4; i++) a[i] = As[k][ty * 4 + i];
#pragma unroll
            for (int j = 0; j < 4; j++) b[j] = Bs[k][tx * 4 + j];
#pragma unroll
            for (int i = 0; i < 4; i++)
#pragma unroll
                for (int j = 0; j < 4; j++) acc[i][j] += a[i] * b[j];
        }
        __syncthreads();
    }
#pragma unroll
    for (int i = 0; i < 4; i++) {
        int r = row0 + ty * 4 + i;
        if (r < M) {
#pragma unroll
            for (int j = 0; j < 4; j++)
                C[(long)r * N + col0 + tx * 4 + j] = acc[i][j];
        }
    }
}

// ---------------- per-node gather aggregation, fused self-loop + bias (+relu) ----------------
// One block per node, DV4 threads (DV4 = D/4 float4 lanes).
template<int DV4, bool RELU>
__global__ __launch_bounds__(DV4) void gather_nodes(const float4* __restrict__ h,
                                                    const int* __restrict__ off,
                                                    const int* __restrict__ csr_src,
                                                    const float* __restrict__ csr_w,
                                                    const float* __restrict__ dis,
                                                    const float4* __restrict__ bias,
                                                    float4* __restrict__ out) {
    int n = blockIdx.x;
    int f = threadIdx.x;
    float dn = dis[n];
    float4 hv = h[n * DV4 + f];
    // acc = dn*h[n] + sum dis[s]*h[s]; final acc*dn gives invdeg*h[n] + dn*dis[s]*h[s]
    float ax = dn * hv.x, ay = dn * hv.y, az = dn * hv.z, aw = dn * hv.w;
    int kb = off[n], ke = off[n + 1];
    for (int k = kb; k < ke; k++) {
        int s = csr_src[k];
        float w = csr_w[k];
        float4 v = h[s * DV4 + f];
        ax += w * v.x; ay += w * v.y; az += w * v.z; aw += w * v.w;
    }
    float4 bb = bias[f];
    float4 o;
    o.x = ax * dn + bb.x;
    o.y = ay * dn + bb.y;
    o.z = az * dn + bb.z;
    o.w = aw * dn + bb.w;
    if (RELU) {
        o.x = fmaxf(o.x, 0.0f); o.y = fmaxf(o.y, 0.0f);
        o.z = fmaxf(o.z, 0.0f); o.w = fmaxf(o.w, 0.0f);
    }
    out[n * DV4 + f] = o;
}

// ---------------- pooling accumulate: one block per node ----------------
__global__ __launch_bounds__(256) void pool_acc(const float* __restrict__ agg,
                                                const int* __restrict__ batch,
                                                float* __restrict__ pool,
                                                float* __restrict__ cnt) {
    int n = blockIdx.x;
    int t = threadIdx.x;  // 256 = D_OUT
    int g = batch[n];
    atomicAdd(&pool[g * 256 + t], agg[n * 256 + t]);
    if (t == 0) atomicAdd(&cnt[g], 1.0f);
}

// ---------------- head: mean, L2-normalize, concat, 3-layer MLP ----------------
// (b4 was already added per-node in the layer-4 gather; mean preserves it.)
__global__ __launch_bounds__(256) void head(const float* __restrict__ pool,
                                            const float* __restrict__ cnt,
                                            const float* __restrict__ vec,
                                            const float* __restrict__ cW1, const float* __restrict__ cb1,
                                            const float* __restrict__ cW2, const float* __restrict__ cb2,
                                            const float* __restrict__ cW3, const float* __restrict__ cb3,
                                            float* __restrict__ out) {
    int g = blockIdx.x;
    int t = threadIdx.x;
    __shared__ float comb[512];
    __shared__ float z1s[256];
    __shared__ float z2s[64];
    __shared__ float red[4];

    float c = fmaxf(cnt[g], 1.0f);
    float pm = pool[g * 256 + t] / c;

    float ss = pm * pm;
#pragma unroll
    for (int o = 32; o; o >>= 1) ss += __shfl_down(ss, o);
    if ((t & 63) == 0) red[t >> 6] = ss;
    __syncthreads();
    if (t == 0) {
        float tot = red[0] + red[1] + red[2] + red[3];
        red[0] = 1.0f / fmaxf(sqrtf(tot), 1e-12f);
    }
    __syncthreads();
    float scale = red[0];
    comb[t] = pm * scale;
    comb[256 + t] = vec[g * 256 + t];
    __syncthreads();

    float s1 = cb1[t];
    for (int i = 0; i < 512; i++) s1 += comb[i] * cW1[i * 256 + t];
    z1s[t] = fmaxf(s1, 0.0f);
    __syncthreads();

    if (t < 64) {
        float s2 = cb2[t];
        for (int i = 0; i < 256; i++) s2 += z1s[i] * cW2[i * 64 + t];
        z2s[t] = fmaxf(s2, 0.0f);
    }
    __syncthreads();

    if (t == 0) {
        float s3 = cb3[0];
        for (int i = 0; i < 64; i++) s3 += z2s[i] * cW3[i];
        out[g] = 1.0f / (1.0f + expf(-s3));
    }
}

extern "C" void kernel_launch(void* const* d_in, const int* in_sizes, int n_in,
                              void* d_out, int out_size, void* d_ws, size_t ws_size,
                              hipStream_t stream) {
    const float* x   = (const float*)d_in[0];
    const int*   ei  = (const int*)d_in[1];   // int32 from harness
    const int*   bat = (const int*)d_in[2];
    const float* vec = (const float*)d_in[3];
    const float* W1 = (const float*)d_in[4];
    const float* b1 = (const float*)d_in[5];
    const float* W2 = (const float*)d_in[6];
    const float* b2 = (const float*)d_in[7];
    const float* W3 = (const float*)d_in[8];
    const float* b3 = (const float*)d_in[9];
    const float* W4 = (const float*)d_in[10];
    const float* b4 = (const float*)d_in[11];
    const float* cW1 = (const float*)d_in[12];
    const float* cb1 = (const float*)d_in[13];
    const float* cW2 = (const float*)d_in[14];
    const float* cb2 = (const float*)d_in[15];
    const float* cW3 = (const float*)d_in[16];
    const float* cb3 = (const float*)d_in[17];

    const int* srcI = ei;
    const int* dstI = ei + N_EDGES;

    char* base = (char*)d_ws;
    float* dis     = (float*)base;                         base += N_NODES * 4;
    float* h       = (float*)base;                         base += N_NODES * 512 * 4;
    float* agg     = (float*)base;                         base += N_NODES * 512 * 4;
    float* pool    = (float*)base;                         base += NGRAPH * 256 * 4;
    float* cnt     = (float*)base;                         base += NGRAPH * 4;
    int*   degc    = (int*)base;                           base += N_NODES * 4;
    int*   off     = (int*)base;                           base += (N_NODES + 1) * 4;
    int*   fc      = (int*)base;                           base += N_NODES * 4;
    int*   csr_src = (int*)base;                           base += N_EDGES * 4;
    float* csr_w   = (float*)base;                         base += N_EDGES * 4;

    // ---- CSR build ----
    zero_i32<<<(2 * N_NODES + 255) / 256, 256, 0, stream>>>(degc, 2 * N_NODES); // degc + fc (adjacent? no)
    // degc and fc are not adjacent; zero separately to be safe:
    zero_i32<<<(N_NODES + 255) / 256, 256, 0, stream>>>(fc, N_NODES);
    deg_count<<<(N_EDGES + 255) / 256, 256, 0, stream>>>(dstI, degc, N_EDGES);
    deg_fin<<<(N_NODES + 255) / 256, 256, 0, stream>>>(degc, dis, N_NODES);
    scan_offsets<<<1, 1024, 0, stream>>>(degc, off, N_NODES);
    csr_fill<<<(N_EDGES + 255) / 256, 256, 0, stream>>>(srcI, dstI, off, fc, dis, csr_src, csr_w, N_EDGES);

    const int M = N_NODES;

    // ---- layer 1: x[10000,1280] @ W1 -> h; gather+b1+relu -> agg ----
    {
        dim3 grid(512 / 64, (M + 63) / 64);
        gemm_f32<<<grid, 256, 0, stream>>>(x, W1, h, M, 1280, 512);
        gather_nodes<128, true><<<M, 128, 0, stream>>>((const float4*)h, off, csr_src, csr_w, dis,
                                                       (const float4*)b1, (float4*)agg);
    }
    // ---- layers 2,3 ----
    const float* Ws[2] = {W2, W3};
    const float* bs[2] = {b2, b3};
    for (int l = 0; l < 2; l++) {
        dim3 grid(512 / 64, (M + 63) / 64);
        gemm_f32<<<grid, 256, 0, stream>>>(agg, Ws[l], h, M, 512, 512);
        gather_nodes<128, true><<<M, 128, 0, stream>>>((const float4*)h, off, csr_src, csr_w, dis,
                                                       (const float4*)bs[l], (float4*)agg);
    }
    // ---- layer 4: [10000,512] @ W4[512,256]; gather + b4, no relu ----
    {
        dim3 grid(256 / 64, (M + 63) / 64);
        gemm_f32<<<grid, 256, 0, stream>>>(agg, W4, h, M, 512, 256);
        gather_nodes<64, false><<<M, 64, 0, stream>>>((const float4*)h, off, csr_src, csr_w, dis,
                                                      (const float4*)b4, (float4*)agg);
    }

    // ---- pooling ----
    zero_f32<<<(NGRAPH * 256 + NGRAPH + 255) / 256, 256, 0, stream>>>(pool, NGRAPH * 256 + NGRAPH);
    pool_acc<<<M, 256, 0, stream>>>(agg, bat, pool, cnt);

    // ---- head ----
    head<<<NGRAPH, 256, 0, stream>>>(pool, cnt, vec, cW1, cb1, cW2, cb2, cW3, cb3, (float*)d_out);
}

// Round 4
// 490.173 us; speedup vs baseline: 9.4414x; 2.1469x over previous
//
#include <hip/hip_runtime.h>
#include <hip/hip_bf16.h>

// ToxDL GCN, round 3: bf16 MFMA GEMMs + bf16 gather path.
// act(bf16) @ Wt(bf16,[N][K]) -> h(bf16) -> CSR gather (fp32 accum) -> next act(bf16)
// Layer 4 gather emits fp32 for pooling; head stays fp32.

#define N_NODES 10000
#define N_EDGES 160000
#define NGRAPH  64
#define MPAD    10112   // 79*128

typedef __attribute__((ext_vector_type(8))) short short8;
typedef __attribute__((ext_vector_type(4))) float f32x4;
typedef __attribute__((ext_vector_type(4))) unsigned short u16x4;

__device__ __forceinline__ unsigned short f2bf(float f) {
    unsigned u = __float_as_uint(f);
    return (unsigned short)((u + 0x7FFFu + ((u >> 16) & 1u)) >> 16);
}
__device__ __forceinline__ float bf2f(unsigned short u) {
    return __uint_as_float(((unsigned)u) << 16);
}
__device__ __forceinline__ void gl_lds16(const void* g, void* l) {
    __builtin_amdgcn_global_load_lds(
        (const __attribute__((address_space(1))) unsigned*)g,
        (__attribute__((address_space(3))) unsigned*)l, 16, 0, 0);
}

// ---------------- utility ----------------
__global__ __launch_bounds__(256) void zero_i32(int* p, int n) {
    int i = blockIdx.x * 256 + threadIdx.x;
    if (i < n) p[i] = 0;
}
__global__ __launch_bounds__(256) void zero_f32(float* p, int n) {
    int i = blockIdx.x * 256 + threadIdx.x;
    if (i < n) p[i] = 0.0f;
}

// ---------------- convert fp32 -> bf16 (flat, 4/thread) ----------------
__global__ __launch_bounds__(256) void conv_bf16(const float4* __restrict__ in,
                                                 u16x4* __restrict__ out, int n4) {
    int i = blockIdx.x * 256 + threadIdx.x;
    if (i >= n4) return;
    float4 v = in[i];
    u16x4 o;
    o.x = f2bf(v.x); o.y = f2bf(v.y); o.z = f2bf(v.z); o.w = f2bf(v.w);
    out[i] = o;
}

// ---------------- W[K][N] fp32 -> Wt[N][K] bf16 ----------------
__global__ __launch_bounds__(256) void conv_transpose_w(const float* __restrict__ W,
                                                        unsigned short* __restrict__ Wt,
                                                        int K, int N) {
    __shared__ float t[32][33];
    int k0 = blockIdx.x * 32, n0 = blockIdx.y * 32;
    int tx = threadIdx.x & 31, ty = threadIdx.x >> 5;  // ty 0..7
#pragma unroll
    for (int i = 0; i < 4; i++)
        t[ty + i * 8][tx] = W[(size_t)(k0 + ty + i * 8) * N + n0 + tx];
    __syncthreads();
#pragma unroll
    for (int i = 0; i < 4; i++)
        Wt[(size_t)(n0 + ty + i * 8) * K + k0 + tx] = f2bf(t[tx][ty + i * 8]);
}

// ---------------- CSR build ----------------
__global__ __launch_bounds__(256) void deg_count(const int* __restrict__ dst, int* __restrict__ degc, int E) {
    int e = blockIdx.x * 256 + threadIdx.x;
    if (e < E) atomicAdd(&degc[dst[e]], 1);
}
__global__ __launch_bounds__(256) void deg_fin(const int* __restrict__ degc, float* __restrict__ dis, int n) {
    int i = blockIdx.x * 256 + threadIdx.x;
    if (i < n) dis[i] = 1.0f / sqrtf((float)(degc[i] + 1));
}
__global__ __launch_bounds__(1024) void scan_offsets(const int* __restrict__ cnt,
                                                     int* __restrict__ off, int n) {
    __shared__ int buf[1024];
    __shared__ int carry;
    int t = threadIdx.x;
    if (t == 0) { carry = 0; off[0] = 0; }
    __syncthreads();
    for (int base = 0; base < n; base += 1024) {
        int v = (base + t < n) ? cnt[base + t] : 0;
        buf[t] = v;
        __syncthreads();
#pragma unroll
        for (int o = 1; o < 1024; o <<= 1) {
            int add = (t >= o) ? buf[t - o] : 0;
            __syncthreads();
            buf[t] += add;
            __syncthreads();
        }
        if (base + t < n) off[base + t + 1] = buf[t] + carry;
        __syncthreads();
        if (t == 0) carry += buf[1023];
        __syncthreads();
    }
}
__global__ __launch_bounds__(256) void csr_fill(const int* __restrict__ srcI,
                                                const int* __restrict__ dstI,
                                                const int* __restrict__ off,
                                                int* __restrict__ fc,
                                                const float* __restrict__ dis,
                                                int* __restrict__ csr_src,
                                                float* __restrict__ csr_w, int E) {
    int e = blockIdx.x * 256 + threadIdx.x;
    if (e >= E) return;
    int d = dstI[e];
    int s = srcI[e];
    int pos = off[d] + atomicAdd(&fc[d], 1);
    csr_src[pos] = s;
    csr_w[pos] = dis[s];
}

// ---------------- bf16 MFMA GEMM: C[MPAD][N](bf16) = A[<=10000][K](bf16) @ Bt[N][K]^T ----------------
// 128x128 tile, BK=64, 256 threads (4 waves, 2x2 of 64x64), mfma 16x16x32.
__global__ __launch_bounds__(256) void gemm_bf16(const unsigned short* __restrict__ A,
                                                 const unsigned short* __restrict__ Bt,
                                                 unsigned short* __restrict__ C,
                                                 int K, int N) {
    __shared__ short lA[128 * 64];
    __shared__ short lB[128 * 64];
    int tid = threadIdx.x;
    int lane = tid & 63;
    int wave = tid >> 6;
    int rm = blockIdx.y, cn = blockIdx.x;
    int wr = wave >> 1, wc = wave & 1;

    f32x4 acc[4][4];
#pragma unroll
    for (int m = 0; m < 4; m++)
#pragma unroll
        for (int n = 0; n < 4; n++) acc[m][n] = (f32x4){0.f, 0.f, 0.f, 0.f};

    int lr = lane >> 3;          // row within 8-row segment
    int lc = (lane & 7) * 8;     // elem offset within BK=64

    for (int k0 = 0; k0 < K; k0 += 64) {
        __syncthreads();
#pragma unroll
        for (int i = 0; i < 4; i++) {
            int s = wave * 4 + i;
            int row = rm * 128 + s * 8 + lr;
            if (row > N_NODES - 1) row = N_NODES - 1;   // clamp tail (dup rows, never read downstream)
            gl_lds16(A + (size_t)row * K + k0 + lc, &lA[s * 512]);
        }
#pragma unroll
        for (int i = 0; i < 4; i++) {
            int s = wave * 4 + i;
            int row = cn * 128 + s * 8 + lr;            // always < N
            gl_lds16(Bt + (size_t)row * K + k0 + lc, &lB[s * 512]);
        }
        __syncthreads();
#pragma unroll
        for (int kk = 0; kk < 64; kk += 32) {
            short8 a[4], b[4];
#pragma unroll
            for (int m = 0; m < 4; m++)
                a[m] = *(const short8*)&lA[(wr * 64 + m * 16 + (lane & 15)) * 64 + kk + (lane >> 4) * 8];
#pragma unroll
            for (int n = 0; n < 4; n++)
                b[n] = *(const short8*)&lB[(wc * 64 + n * 16 + (lane & 15)) * 64 + kk + (lane >> 4) * 8];
#pragma unroll
            for (int m = 0; m < 4; m++)
#pragma unroll
                for (int n = 0; n < 4; n++)
                    acc[m][n] = __builtin_amdgcn_mfma_f32_16x16x32_bf16(a[m], b[n], acc[m][n], 0, 0, 0);
        }
    }
    int r0 = rm * 128 + wr * 64 + (lane >> 4) * 4;
    int c0 = cn * 128 + wc * 64 + (lane & 15);
#pragma unroll
    for (int m = 0; m < 4; m++)
#pragma unroll
        for (int n = 0; n < 4; n++)
#pragma unroll
            for (int j = 0; j < 4; j++)
                C[(size_t)(r0 + m * 16 + j) * N + c0 + n * 16] = f2bf(acc[m][n][j]);
}

// ---------------- per-node CSR gather, fused self-loop + bias (+relu) ----------------
// D features; D/4 threads per block; h is bf16. OUTBF: emit bf16 (next GEMM) else fp32.
template<int D, bool RELU, bool OUTBF>
__global__ __launch_bounds__(D / 4) void gather_nodes(const unsigned short* __restrict__ h,
                                                      const int* __restrict__ off,
                                                      const int* __restrict__ csr_src,
                                                      const float* __restrict__ csr_w,
                                                      const float* __restrict__ dis,
                                                      const float4* __restrict__ bias,
                                                      void* __restrict__ outp) {
    int n = blockIdx.x;
    int f = threadIdx.x;
    float dn = dis[n];
    u16x4 hv = ((const u16x4*)(h + (size_t)n * D))[f];
    float ax = dn * bf2f(hv.x), ay = dn * bf2f(hv.y), az = dn * bf2f(hv.z), aw = dn * bf2f(hv.w);
    int kb = off[n], ke = off[n + 1];
    for (int k = kb; k < ke; k++) {
        int s = csr_src[k];
        float w = csr_w[k];
        u16x4 v = ((const u16x4*)(h + (size_t)s * D))[f];
        ax += w * bf2f(v.x); ay += w * bf2f(v.y); az += w * bf2f(v.z); aw += w * bf2f(v.w);
    }
    float4 bb = bias[f];
    float ox = ax * dn + bb.x, oy = ay * dn + bb.y, oz = az * dn + bb.z, ow = aw * dn + bb.w;
    if (RELU) {
        ox = fmaxf(ox, 0.f); oy = fmaxf(oy, 0.f); oz = fmaxf(oz, 0.f); ow = fmaxf(ow, 0.f);
    }
    if (OUTBF) {
        u16x4 o; o.x = f2bf(ox); o.y = f2bf(oy); o.z = f2bf(oz); o.w = f2bf(ow);
        ((u16x4*)outp)[(size_t)n * (D / 4) + f] = o;
    } else {
        ((float4*)outp)[(size_t)n * (D / 4) + f] = make_float4(ox, oy, oz, ow);
    }
}

// ---------------- pooling ----------------
__global__ __launch_bounds__(256) void pool_acc(const float* __restrict__ agg,
                                                const int* __restrict__ batch,
                                                float* __restrict__ pool,
                                                float* __restrict__ cnt) {
    int n = blockIdx.x;
    int t = threadIdx.x;
    int g = batch[n];
    atomicAdd(&pool[g * 256 + t], agg[n * 256 + t]);
    if (t == 0) atomicAdd(&cnt[g], 1.0f);
}

// ---------------- head ----------------
__global__ __launch_bounds__(256) void head(const float* __restrict__ pool,
                                            const float* __restrict__ cnt,
                                            const float* __restrict__ vec,
                                            const float* __restrict__ cW1, const float* __restrict__ cb1,
                                            const float* __restrict__ cW2, const float* __restrict__ cb2,
                                            const float* __restrict__ cW3, const float* __restrict__ cb3,
                                            float* __restrict__ out) {
    int g = blockIdx.x;
    int t = threadIdx.x;
    __shared__ float comb[512];
    __shared__ float z1s[256];
    __shared__ float z2s[64];
    __shared__ float red[4];

    float c = fmaxf(cnt[g], 1.0f);
    float pm = pool[g * 256 + t] / c;

    float ss = pm * pm;
#pragma unroll
    for (int o = 32; o; o >>= 1) ss += __shfl_down(ss, o);
    if ((t & 63) == 0) red[t >> 6] = ss;
    __syncthreads();
    if (t == 0) {
        float tot = red[0] + red[1] + red[2] + red[3];
        red[0] = 1.0f / fmaxf(sqrtf(tot), 1e-12f);
    }
    __syncthreads();
    float scale = red[0];
    comb[t] = pm * scale;
    comb[256 + t] = vec[g * 256 + t];
    __syncthreads();

    float s1 = cb1[t];
    for (int i = 0; i < 512; i++) s1 += comb[i] * cW1[i * 256 + t];
    z1s[t] = fmaxf(s1, 0.0f);
    __syncthreads();

    if (t < 64) {
        float s2 = cb2[t];
        for (int i = 0; i < 256; i++) s2 += z1s[i] * cW2[i * 64 + t];
        z2s[t] = fmaxf(s2, 0.0f);
    }
    __syncthreads();

    if (t == 0) {
        float s3 = cb3[0];
        for (int i = 0; i < 64; i++) s3 += z2s[i] * cW3[i];
        out[g] = 1.0f / (1.0f + expf(-s3));
    }
}

extern "C" void kernel_launch(void* const* d_in, const int* in_sizes, int n_in,
                              void* d_out, int out_size, void* d_ws, size_t ws_size,
                              hipStream_t stream) {
    const float* x   = (const float*)d_in[0];
    const int*   ei  = (const int*)d_in[1];
    const int*   bat = (const int*)d_in[2];
    const float* vec = (const float*)d_in[3];
    const float* W1 = (const float*)d_in[4];
    const float* b1 = (const float*)d_in[5];
    const float* W2 = (const float*)d_in[6];
    const float* b2 = (const float*)d_in[7];
    const float* W3 = (const float*)d_in[8];
    const float* b3 = (const float*)d_in[9];
    const float* W4 = (const float*)d_in[10];
    const float* b4 = (const float*)d_in[11];
    const float* cW1 = (const float*)d_in[12];
    const float* cb1 = (const float*)d_in[13];
    const float* cW2 = (const float*)d_in[14];
    const float* cb2 = (const float*)d_in[15];
    const float* cW3 = (const float*)d_in[16];
    const float* cb3 = (const float*)d_in[17];

    const int* srcI = ei;
    const int* dstI = ei + N_EDGES;

    char* base = (char*)d_ws;
    float* dis      = (float*)base;            base += N_NODES * 4;
    int*   degc     = (int*)base;              base += N_NODES * 4;
    int*   off      = (int*)base;              base += (N_NODES + 1) * 4;
    int*   fc       = (int*)base;              base += N_NODES * 4 + 4;
    int*   csr_src  = (int*)base;              base += N_EDGES * 4;
    float* csr_w    = (float*)base;            base += N_EDGES * 4;
    float* pool     = (float*)base;            base += NGRAPH * 256 * 4;
    float* cnt      = (float*)base;            base += NGRAPH * 4 + 4;
    unsigned short* xb   = (unsigned short*)base;  base += (size_t)N_NODES * 1280 * 2;  // also aliased by agg4
    unsigned short* W1t  = (unsigned short*)base;  base += 512 * 1280 * 2;
    unsigned short* W2t  = (unsigned short*)base;  base += 512 * 512 * 2;
    unsigned short* W3t  = (unsigned short*)base;  base += 512 * 512 * 2;
    unsigned short* W4t  = (unsigned short*)base;  base += 256 * 512 * 2;
    unsigned short* h    = (unsigned short*)base;  base += (size_t)MPAD * 512 * 2;
    unsigned short* aggb = (unsigned short*)base;  base += (size_t)N_NODES * 512 * 2;
    float* agg4 = (float*)xb;  // alias: xb dead after GEMM1, agg4 written by gather4

    // ---- conversions ----
    conv_bf16<<<(N_NODES * 1280 / 4 + 255) / 256, 256, 0, stream>>>((const float4*)x, (u16x4*)xb, N_NODES * 1280 / 4);
    conv_transpose_w<<<dim3(1280 / 32, 512 / 32), 256, 0, stream>>>(W1, W1t, 1280, 512);
    conv_transpose_w<<<dim3(512 / 32, 512 / 32), 256, 0, stream>>>(W2, W2t, 512, 512);
    conv_transpose_w<<<dim3(512 / 32, 512 / 32), 256, 0, stream>>>(W3, W3t, 512, 512);
    conv_transpose_w<<<dim3(512 / 32, 256 / 32), 256, 0, stream>>>(W4, W4t, 512, 256);

    // ---- CSR build ----
    zero_i32<<<(N_NODES + 255) / 256, 256, 0, stream>>>(degc, N_NODES);
    zero_i32<<<(N_NODES + 255) / 256, 256, 0, stream>>>(fc, N_NODES);
    deg_count<<<(N_EDGES + 255) / 256, 256, 0, stream>>>(dstI, degc, N_EDGES);
    deg_fin<<<(N_NODES + 255) / 256, 256, 0, stream>>>(degc, dis, N_NODES);
    scan_offsets<<<1, 1024, 0, stream>>>(degc, off, N_NODES);
    csr_fill<<<(N_EDGES + 255) / 256, 256, 0, stream>>>(srcI, dstI, off, fc, dis, csr_src, csr_w, N_EDGES);

    // ---- layer 1 ----
    gemm_bf16<<<dim3(512 / 128, MPAD / 128), 256, 0, stream>>>(xb, W1t, h, 1280, 512);
    gather_nodes<512, true, true><<<N_NODES, 128, 0, stream>>>(h, off, csr_src, csr_w, dis,
                                                               (const float4*)b1, aggb);
    // ---- layer 2 ----
    gemm_bf16<<<dim3(512 / 128, MPAD / 128), 256, 0, stream>>>(aggb, W2t, h, 512, 512);
    gather_nodes<512, true, true><<<N_NODES, 128, 0, stream>>>(h, off, csr_src, csr_w, dis,
                                                               (const float4*)b2, aggb);
    // ---- layer 3 ----
    gemm_bf16<<<dim3(512 / 128, MPAD / 128), 256, 0, stream>>>(aggb, W3t, h, 512, 512);
    gather_nodes<512, true, true><<<N_NODES, 128, 0, stream>>>(h, off, csr_src, csr_w, dis,
                                                               (const float4*)b3, aggb);
    // ---- layer 4 (no relu, fp32 out) ----
    gemm_bf16<<<dim3(256 / 128, MPAD / 128), 256, 0, stream>>>(aggb, W4t, h, 512, 256);
    gather_nodes<256, false, false><<<N_NODES, 64, 0, stream>>>(h, off, csr_src, csr_w, dis,
                                                                (const float4*)b4, agg4);

    // ---- pooling ----
    zero_f32<<<(NGRAPH * 256 + NGRAPH + 255) / 256, 256, 0, stream>>>(pool, NGRAPH * 256 + NGRAPH);
    pool_acc<<<N_NODES, 256, 0, stream>>>(agg4, bat, pool, cnt);

    // ---- head ----
    head<<<NGRAPH, 256, 0, stream>>>(pool, cnt, vec, cW1, cb1, cW2, cb2, cW3, cb3, (float*)d_out);
}

// Round 5
// 442.688 us; speedup vs baseline: 10.4541x; 1.1073x over previous
//
#include <hip/hip_runtime.h>
#include <hip/hip_bf16.h>

// ToxDL GCN, round 4: fused sorted-batch pooling + head (no pool atomics).
// act(bf16) @ Wt(bf16,[N][K]) -> h(bf16) -> CSR gather (fp32 accum) -> next act(bf16)
// Layer 4 gather emits fp32; pool_head does segment-sum (batch is sorted), L2-norm, MLP.

#define N_NODES 10000
#define N_EDGES 160000
#define NGRAPH  64
#define MPAD    10112   // 79*128

typedef __attribute__((ext_vector_type(8))) short short8;
typedef __attribute__((ext_vector_type(4))) float f32x4;
typedef __attribute__((ext_vector_type(4))) unsigned short u16x4;

__device__ __forceinline__ unsigned short f2bf(float f) {
    unsigned u = __float_as_uint(f);
    return (unsigned short)((u + 0x7FFFu + ((u >> 16) & 1u)) >> 16);
}
__device__ __forceinline__ float bf2f(unsigned short u) {
    return __uint_as_float(((unsigned)u) << 16);
}
__device__ __forceinline__ void gl_lds16(const void* g, void* l) {
    __builtin_amdgcn_global_load_lds(
        (const __attribute__((address_space(1))) unsigned*)g,
        (__attribute__((address_space(3))) unsigned*)l, 16, 0, 0);
}

// ---------------- utility ----------------
__global__ __launch_bounds__(256) void zero_i32(int* p, int n) {
    int i = blockIdx.x * 256 + threadIdx.x;
    if (i < n) p[i] = 0;
}

// ---------------- convert fp32 -> bf16 (flat, 4/thread) ----------------
__global__ __launch_bounds__(256) void conv_bf16(const float4* __restrict__ in,
                                                 u16x4* __restrict__ out, int n4) {
    int i = blockIdx.x * 256 + threadIdx.x;
    if (i >= n4) return;
    float4 v = in[i];
    u16x4 o;
    o.x = f2bf(v.x); o.y = f2bf(v.y); o.z = f2bf(v.z); o.w = f2bf(v.w);
    out[i] = o;
}

// ---------------- W[K][N] fp32 -> Wt[N][K] bf16 ----------------
__global__ __launch_bounds__(256) void conv_transpose_w(const float* __restrict__ W,
                                                        unsigned short* __restrict__ Wt,
                                                        int K, int N) {
    __shared__ float t[32][33];
    int k0 = blockIdx.x * 32, n0 = blockIdx.y * 32;
    int tx = threadIdx.x & 31, ty = threadIdx.x >> 5;  // ty 0..7
#pragma unroll
    for (int i = 0; i < 4; i++)
        t[ty + i * 8][tx] = W[(size_t)(k0 + ty + i * 8) * N + n0 + tx];
    __syncthreads();
#pragma unroll
    for (int i = 0; i < 4; i++)
        Wt[(size_t)(n0 + ty + i * 8) * K + k0 + tx] = f2bf(t[tx][ty + i * 8]);
}

// ---------------- CSR build ----------------
__global__ __launch_bounds__(256) void deg_count(const int* __restrict__ dst, int* __restrict__ degc, int E) {
    int e = blockIdx.x * 256 + threadIdx.x;
    if (e < E) atomicAdd(&degc[dst[e]], 1);
}
__global__ __launch_bounds__(256) void deg_fin(const int* __restrict__ degc, float* __restrict__ dis, int n) {
    int i = blockIdx.x * 256 + threadIdx.x;
    if (i < n) dis[i] = 1.0f / sqrtf((float)(degc[i] + 1));
}
__global__ __launch_bounds__(1024) void scan_offsets(const int* __restrict__ cnt,
                                                     int* __restrict__ off, int n) {
    __shared__ int buf[1024];
    __shared__ int carry;
    int t = threadIdx.x;
    if (t == 0) { carry = 0; off[0] = 0; }
    __syncthreads();
    for (int base = 0; base < n; base += 1024) {
        int v = (base + t < n) ? cnt[base + t] : 0;
        buf[t] = v;
        __syncthreads();
#pragma unroll
        for (int o = 1; o < 1024; o <<= 1) {
            int add = (t >= o) ? buf[t - o] : 0;
            __syncthreads();
            buf[t] += add;
            __syncthreads();
        }
        if (base + t < n) off[base + t + 1] = buf[t] + carry;
        __syncthreads();
        if (t == 0) carry += buf[1023];
        __syncthreads();
    }
}
__global__ __launch_bounds__(256) void csr_fill(const int* __restrict__ srcI,
                                                const int* __restrict__ dstI,
                                                const int* __restrict__ off,
                                                int* __restrict__ fc,
                                                const float* __restrict__ dis,
                                                int* __restrict__ csr_src,
                                                float* __restrict__ csr_w, int E) {
    int e = blockIdx.x * 256 + threadIdx.x;
    if (e >= E) return;
    int d = dstI[e];
    int s = srcI[e];
    int pos = off[d] + atomicAdd(&fc[d], 1);
    csr_src[pos] = s;
    csr_w[pos] = dis[s];
}

// ---------------- bf16 MFMA GEMM: C[MPAD][N](bf16) = A[<=10000][K](bf16) @ Bt[N][K]^T ----------------
// 128x128 tile, BK=64, 256 threads (4 waves, 2x2 of 64x64), mfma 16x16x32.
__global__ __launch_bounds__(256) void gemm_bf16(const unsigned short* __restrict__ A,
                                                 const unsigned short* __restrict__ Bt,
                                                 unsigned short* __restrict__ C,
                                                 int K, int N) {
    __shared__ short lA[128 * 64];
    __shared__ short lB[128 * 64];
    int tid = threadIdx.x;
    int lane = tid & 63;
    int wave = tid >> 6;
    int rm = blockIdx.y, cn = blockIdx.x;
    int wr = wave >> 1, wc = wave & 1;

    f32x4 acc[4][4];
#pragma unroll
    for (int m = 0; m < 4; m++)
#pragma unroll
        for (int n = 0; n < 4; n++) acc[m][n] = (f32x4){0.f, 0.f, 0.f, 0.f};

    int lr = lane >> 3;          // row within 8-row segment
    int lc = (lane & 7) * 8;     // elem offset within BK=64

    for (int k0 = 0; k0 < K; k0 += 64) {
        __syncthreads();
#pragma unroll
        for (int i = 0; i < 4; i++) {
            int s = wave * 4 + i;
            int row = rm * 128 + s * 8 + lr;
            if (row > N_NODES - 1) row = N_NODES - 1;   // clamp tail (dup rows, never read downstream)
            gl_lds16(A + (size_t)row * K + k0 + lc, &lA[s * 512]);
        }
#pragma unroll
        for (int i = 0; i < 4; i++) {
            int s = wave * 4 + i;
            int row = cn * 128 + s * 8 + lr;            // always < N
            gl_lds16(Bt + (size_t)row * K + k0 + lc, &lB[s * 512]);
        }
        __syncthreads();
#pragma unroll
        for (int kk = 0; kk < 64; kk += 32) {
            short8 a[4], b[4];
#pragma unroll
            for (int m = 0; m < 4; m++)
                a[m] = *(const short8*)&lA[(wr * 64 + m * 16 + (lane & 15)) * 64 + kk + (lane >> 4) * 8];
#pragma unroll
            for (int n = 0; n < 4; n++)
                b[n] = *(const short8*)&lB[(wc * 64 + n * 16 + (lane & 15)) * 64 + kk + (lane >> 4) * 8];
#pragma unroll
            for (int m = 0; m < 4; m++)
#pragma unroll
                for (int n = 0; n < 4; n++)
                    acc[m][n] = __builtin_amdgcn_mfma_f32_16x16x32_bf16(a[m], b[n], acc[m][n], 0, 0, 0);
        }
    }
    int r0 = rm * 128 + wr * 64 + (lane >> 4) * 4;
    int c0 = cn * 128 + wc * 64 + (lane & 15);
#pragma unroll
    for (int m = 0; m < 4; m++)
#pragma unroll
        for (int n = 0; n < 4; n++)
#pragma unroll
            for (int j = 0; j < 4; j++)
                C[(size_t)(r0 + m * 16 + j) * N + c0 + n * 16] = f2bf(acc[m][n][j]);
}

// ---------------- per-node CSR gather, fused self-loop + bias (+relu) ----------------
template<int D, bool RELU, bool OUTBF>
__global__ __launch_bounds__(D / 4) void gather_nodes(const unsigned short* __restrict__ h,
                                                      const int* __restrict__ off,
                                                      const int* __restrict__ csr_src,
                                                      const float* __restrict__ csr_w,
                                                      const float* __restrict__ dis,
                                                      const float4* __restrict__ bias,
                                                      void* __restrict__ outp) {
    int n = blockIdx.x;
    int f = threadIdx.x;
    float dn = dis[n];
    u16x4 hv = ((const u16x4*)(h + (size_t)n * D))[f];
    float ax = dn * bf2f(hv.x), ay = dn * bf2f(hv.y), az = dn * bf2f(hv.z), aw = dn * bf2f(hv.w);
    int kb = off[n], ke = off[n + 1];
    for (int k = kb; k < ke; k++) {
        int s = csr_src[k];
        float w = csr_w[k];
        u16x4 v = ((const u16x4*)(h + (size_t)s * D))[f];
        ax += w * bf2f(v.x); ay += w * bf2f(v.y); az += w * bf2f(v.z); aw += w * bf2f(v.w);
    }
    float4 bb = bias[f];
    float ox = ax * dn + bb.x, oy = ay * dn + bb.y, oz = az * dn + bb.z, ow = aw * dn + bb.w;
    if (RELU) {
        ox = fmaxf(ox, 0.f); oy = fmaxf(oy, 0.f); oz = fmaxf(oz, 0.f); ow = fmaxf(ow, 0.f);
    }
    if (OUTBF) {
        u16x4 o; o.x = f2bf(ox); o.y = f2bf(oy); o.z = f2bf(oz); o.w = f2bf(ow);
        ((u16x4*)outp)[(size_t)n * (D / 4) + f] = o;
    } else {
        ((float4*)outp)[(size_t)n * (D / 4) + f] = make_float4(ox, oy, oz, ow);
    }
}

// ---------------- fused pooling + head (batch is sorted -> segment per graph) ----------------
__device__ __forceinline__ int lbound(const int* __restrict__ a, int n, int key) {
    int lo = 0, hi = n;
    while (lo < hi) {
        int mid = (lo + hi) >> 1;
        if (a[mid] < key) lo = mid + 1; else hi = mid;
    }
    return lo;
}

__global__ __launch_bounds__(256) void pool_head(const float* __restrict__ agg,
                                                 const int* __restrict__ batch,
                                                 const float* __restrict__ vec,
                                                 const float* __restrict__ cW1, const float* __restrict__ cb1,
                                                 const float* __restrict__ cW2, const float* __restrict__ cb2,
                                                 const float* __restrict__ cW3, const float* __restrict__ cb3,
                                                 float* __restrict__ out) {
    int g = blockIdx.x;
    int t = threadIdx.x;  // 256 threads = D_OUT
    __shared__ float comb[512];
    __shared__ float z1s[256];
    __shared__ float z2s[64];
    __shared__ float red[4];

    int lo = lbound(batch, N_NODES, g);
    int hi = lbound(batch, N_NODES, g + 1);

    float s = 0.0f;
    for (int n = lo; n < hi; n++) s += agg[(size_t)n * 256 + t];
    float c = fmaxf((float)(hi - lo), 1.0f);
    float pm = s / c;

    float ss = pm * pm;
#pragma unroll
    for (int o = 32; o; o >>= 1) ss += __shfl_down(ss, o);
    if ((t & 63) == 0) red[t >> 6] = ss;
    __syncthreads();
    if (t == 0) {
        float tot = red[0] + red[1] + red[2] + red[3];
        red[0] = 1.0f / fmaxf(sqrtf(tot), 1e-12f);
    }
    __syncthreads();
    float scale = red[0];
    comb[t] = pm * scale;
    comb[256 + t] = vec[g * 256 + t];
    __syncthreads();

    float s1 = cb1[t];
    for (int i = 0; i < 512; i++) s1 += comb[i] * cW1[i * 256 + t];
    z1s[t] = fmaxf(s1, 0.0f);
    __syncthreads();

    if (t < 64) {
        float s2 = cb2[t];
        for (int i = 0; i < 256; i++) s2 += z1s[i] * cW2[i * 64 + t];
        z2s[t] = fmaxf(s2, 0.0f);
    }
    __syncthreads();

    if (t == 0) {
        float s3 = cb3[0];
        for (int i = 0; i < 64; i++) s3 += z2s[i] * cW3[i];
        out[g] = 1.0f / (1.0f + expf(-s3));
    }
}

extern "C" void kernel_launch(void* const* d_in, const int* in_sizes, int n_in,
                              void* d_out, int out_size, void* d_ws, size_t ws_size,
                              hipStream_t stream) {
    const float* x   = (const float*)d_in[0];
    const int*   ei  = (const int*)d_in[1];
    const int*   bat = (const int*)d_in[2];
    const float* vec = (const float*)d_in[3];
    const float* W1 = (const float*)d_in[4];
    const float* b1 = (const float*)d_in[5];
    const float* W2 = (const float*)d_in[6];
    const float* b2 = (const float*)d_in[7];
    const float* W3 = (const float*)d_in[8];
    const float* b3 = (const float*)d_in[9];
    const float* W4 = (const float*)d_in[10];
    const float* b4 = (const float*)d_in[11];
    const float* cW1 = (const float*)d_in[12];
    const float* cb1 = (const float*)d_in[13];
    const float* cW2 = (const float*)d_in[14];
    const float* cb2 = (const float*)d_in[15];
    const float* cW3 = (const float*)d_in[16];
    const float* cb3 = (const float*)d_in[17];

    const int* srcI = ei;
    const int* dstI = ei + N_EDGES;

    char* base = (char*)d_ws;
    float* dis      = (float*)base;            base += N_NODES * 4;
    int*   degc     = (int*)base;              base += N_NODES * 4;
    int*   off      = (int*)base;              base += (N_NODES + 1) * 4;
    int*   fc       = (int*)base;              base += N_NODES * 4 + 4;
    int*   csr_src  = (int*)base;              base += N_EDGES * 4;
    float* csr_w    = (float*)base;            base += N_EDGES * 4;
    unsigned short* xb   = (unsigned short*)base;  base += (size_t)N_NODES * 1280 * 2;  // aliased by agg4 later
    unsigned short* W1t  = (unsigned short*)base;  base += 512 * 1280 * 2;
    unsigned short* W2t  = (unsigned short*)base;  base += 512 * 512 * 2;
    unsigned short* W3t  = (unsigned short*)base;  base += 512 * 512 * 2;
    unsigned short* W4t  = (unsigned short*)base;  base += 256 * 512 * 2;
    unsigned short* h    = (unsigned short*)base;  base += (size_t)MPAD * 512 * 2;
    unsigned short* aggb = (unsigned short*)base;  base += (size_t)N_NODES * 512 * 2;
    float* agg4 = (float*)xb;  // alias: xb dead after GEMM1, agg4 written by gather4

    // ---- conversions ----
    conv_bf16<<<(N_NODES * 1280 / 4 + 255) / 256, 256, 0, stream>>>((const float4*)x, (u16x4*)xb, N_NODES * 1280 / 4);
    conv_transpose_w<<<dim3(1280 / 32, 512 / 32), 256, 0, stream>>>(W1, W1t, 1280, 512);
    conv_transpose_w<<<dim3(512 / 32, 512 / 32), 256, 0, stream>>>(W2, W2t, 512, 512);
    conv_transpose_w<<<dim3(512 / 32, 512 / 32), 256, 0, stream>>>(W3, W3t, 512, 512);
    conv_transpose_w<<<dim3(512 / 32, 256 / 32), 256, 0, stream>>>(W4, W4t, 512, 256);

    // ---- CSR build ----
    zero_i32<<<(N_NODES + 255) / 256, 256, 0, stream>>>(degc, N_NODES);
    zero_i32<<<(N_NODES + 255) / 256, 256, 0, stream>>>(fc, N_NODES);
    deg_count<<<(N_EDGES + 255) / 256, 256, 0, stream>>>(dstI, degc, N_EDGES);
    deg_fin<<<(N_NODES + 255) / 256, 256, 0, stream>>>(degc, dis, N_NODES);
    scan_offsets<<<1, 1024, 0, stream>>>(degc, off, N_NODES);
    csr_fill<<<(N_EDGES + 255) / 256, 256, 0, stream>>>(srcI, dstI, off, fc, dis, csr_src, csr_w, N_EDGES);

    // ---- layer 1 ----
    gemm_bf16<<<dim3(512 / 128, MPAD / 128), 256, 0, stream>>>(xb, W1t, h, 1280, 512);
    gather_nodes<512, true, true><<<N_NODES, 128, 0, stream>>>(h, off, csr_src, csr_w, dis,
                                                               (const float4*)b1, aggb);
    // ---- layer 2 ----
    gemm_bf16<<<dim3(512 / 128, MPAD / 128), 256, 0, stream>>>(aggb, W2t, h, 512, 512);
    gather_nodes<512, true, true><<<N_NODES, 128, 0, stream>>>(h, off, csr_src, csr_w, dis,
                                                               (const float4*)b2, aggb);
    // ---- layer 3 ----
    gemm_bf16<<<dim3(512 / 128, MPAD / 128), 256, 0, stream>>>(aggb, W3t, h, 512, 512);
    gather_nodes<512, true, true><<<N_NODES, 128, 0, stream>>>(h, off, csr_src, csr_w, dis,
                                                               (const float4*)b3, aggb);
    // ---- layer 4 (no relu, fp32 out) ----
    gemm_bf16<<<dim3(256 / 128, MPAD / 128), 256, 0, stream>>>(aggb, W4t, h, 512, 256);
    gather_nodes<256, false, false><<<N_NODES, 64, 0, stream>>>(h, off, csr_src, csr_w, dis,
                                                                (const float4*)b4, agg4);

    // ---- fused pooling + head ----
    pool_head<<<NGRAPH, 256, 0, stream>>>(agg4, bat, vec, cW1, cb1, cW2, cb2, cW3, cb3, (float*)d_out);
}